// Round 21
// baseline (69.446 us; speedup 1.0000x reference)
//
#include <hip/hip_runtime.h>
#include <stdint.h>

namespace {

constexpr int   B_   = 64;
constexpr int   F0_  = 1876;
constexpr int   F0P_ = 1880;      // padded rec length (pads never processed)
constexpr int   NI4_ = 469;       // 1876 / 4 exact
constexpr int   F1_  = 1024;
constexpr int   F2_  = 10;
constexpr int   NT_  = 151;
constexpr float DT_  = 0.02f;
constexpr float SCL_  = 1073741824.0f;      // 2^30 fixed-point scale
constexpr float ISCL_ = 1.0f / 1073741824.0f;

constexpr int NBLK_T = 480;       // 30 i-tiles x 16 j-tiles
constexpr int NBLK_R = 470;       // 64*1880/256 exact

// workspace layout (bytes)
constexpr size_t OFF_W1I4 = 0;                     // 469*1024*16 = 7,684,096
constexpr size_t OFF_KOFF = 7684096;               // 64*1880*2   =   240,640
constexpr size_t OFF_TV   = 7924736;               // 64*1880*4   =   481,280
constexpr size_t OFF_IDX1 = 8406016;               // 64*1024 u8  =    65,536

// ---------------------------------------------------------------------------
// k_prep: (a) blocks < 480:  W1[j][i] f32 -> W1iT4[i4][j][4] int (rn(w*2^30))
//         (b) blocks >= 480: koff16[b][i] = clamp(ceil(ti*50),0,50)*256 (u16,
//             bins row stride 64*4 = 256 B); tvarr[b][i] = ti.
// ---------------------------------------------------------------------------
__global__ __launch_bounds__(256) void k_prep(const float* __restrict__ W1,
                                              const float* __restrict__ ti,
                                              int4* __restrict__ W1iT4,
                                              uint16_t* __restrict__ koff16,
                                              float* __restrict__ tvarr) {
  const int t = threadIdx.x;
  if (blockIdx.x < NBLK_T) {
    __shared__ float tile[64][65];
    const int bx = blockIdx.x;
    const int i0 = (bx % 30) * 64;     // 0..1856
    const int j0 = (bx / 30) * 64;
    const int c = t & 63, r4 = t >> 6;
    for (int jj = r4; jj < 64; jj += 4) {
      int i = i0 + c;
      tile[c][jj] = (i < F0_) ? W1[(size_t)(j0 + jj) * F0_ + i] : 0.0f;
    }
    __syncthreads();
    for (int ii4 = r4; ii4 < 16; ii4 += 4) {
      int i4 = (i0 >> 2) + ii4;
      if (i4 < NI4_) {
        int4 v;
        v.x = __float2int_rn(tile[ii4 * 4 + 0][c] * SCL_);
        v.y = __float2int_rn(tile[ii4 * 4 + 1][c] * SCL_);
        v.z = __float2int_rn(tile[ii4 * 4 + 2][c] * SCL_);
        v.w = __float2int_rn(tile[ii4 * 4 + 3][c] * SCL_);
        W1iT4[(size_t)i4 * F1_ + j0 + c] = v;
      }
    }
  } else {
    int n = (blockIdx.x - NBLK_T) * 256 + t;     // < 120,320
    int b = n / F0P_, i = n - b * F0P_;
    if (i < F0_) {
      float v = ti[(size_t)b * F0_ + i];
      int k = (int)fminf(ceilf(v * 50.0f), 50.0f);   // ti >= 0 -> k >= 0
      koff16[n] = (uint16_t)(k << 8);                // k*256
      tvarr[n]  = v;
    } else {
      koff16[n] = 0;
      tvarr[n]  = 0.0f;                              // pads never processed
    }
  }
}

// ---------------------------------------------------------------------------
// Layer 1 (r19's measured-best kernel, verbatim): 1024 blocks = b*16 + jg
// (XCD = jg%8 -> ~1 MB W slice L2-fit), 512 threads = 8 waves; wave = 64 j
// (lane = j); waves split the 469-i4 range 8 ways.  Rec stream (koff,tv) is
// WAVE-UNIFORM per i4, precomputed in k_prep (r20 A/B: inline computation
// costs +2.7 us of VALU under the DS wall).  Per element TWO ds_add_u32
// into ONE shared bins[2][51][64] array; k wave-uniform -> stride-1,
// conflict-free by construction (r15-r20: 0 conflicts).  int32 adds commute
// -> bit-deterministic (absmax 0.0, r13-r20).  MEASURED WALL: LDS-atomic
// data throughput ~64 lanes x 8 B / 7.4 cyc (u64 vs 2xu32 vs fused all
// ~46-49 us) — bytes are irreducible at the required precision.
// Phase 2: tid<64 fused prefix+crossing.  LDS 26 KB.
// ---------------------------------------------------------------------------
__global__ __launch_bounds__(512, 8) void k_main1(const uint16_t* __restrict__ koff16,
                                                  const float* __restrict__ tvarr,
                                                  const int4* __restrict__ W1iT4,
                                                  uint8_t* __restrict__ idx1) {
  __shared__ int bins[2][51][64];   // [0]=A, [1]=C — one object, contiguous
  const int blk  = blockIdx.x;      // 1024
  const int b    = blk >> 4;
  const int jg   = blk & 15;
  const int tid  = threadIdx.x;
  const int lane = tid & 63;
  const int wv   = __builtin_amdgcn_readfirstlane(tid >> 6);  // 0..7

  {
    int4* p = (int4*)(&bins[0][0][0]);
    for (int s = tid; s < (2 * 51 * 64) / 4; s += 512)
      p[s] = make_int4(0, 0, 0, 0);
  }
  __syncthreads();

  // wave i4-split: 469 = 8*58 + 5
  const int cnt = 58 + (wv < 5 ? 1 : 0);
  const int g0  = wv * 58 + (wv < 5 ? wv : 5);

  const int4*     __restrict__ wp = W1iT4 + (jg << 6) + lane;  // + i4*1024
  const uint16_t* __restrict__ kb = koff16 + (size_t)b * F0P_; // uniform
  const float*    __restrict__ tb = tvarr  + (size_t)b * F0P_; // uniform
  char* const binlane = (char*)(&bins[0][0][0]) + (lane << 2);

#define ELEM(a_, tv_, ko_) {                                                  \
    int c_ = __float2int_rn((float)(a_) * (tv_));                             \
    int* cell = (int*)(binlane + (ko_));                                      \
    atomicAdd(cell, (a_));                  /* ds_add_u32, binA */            \
    atomicAdd(cell + 51 * 64, c_);          /* binC: +13056 B, same array */ }

#pragma unroll 2
  for (int m = 0; m < cnt; ++m) {
    const int i4 = g0 + m;
    int4   wa  = wp[(size_t)i4 << 10];              // coalesced 1 KB/wave
    uint2  kk  = *(const uint2*)(kb + i4 * 4);      // uniform broadcast
    float4 tv4 = *(const float4*)(tb + i4 * 4);     // uniform broadcast
    ELEM(wa.x, tv4.x, kk.x & 0xFFFFu);
    ELEM(wa.y, tv4.y, kk.x >> 16);
    ELEM(wa.z, tv4.z, kk.y & 0xFFFFu);
    ELEM(wa.w, tv4.w, kk.y >> 16);
  }
#undef ELEM
  __syncthreads();

  // phase 2: tid < 64, thread owns j = jg*64 + tid. Fused prefix + crossing.
  if (tid < 64) {
    float sa = 0.f, sc = 0.f;
    int cnd = NT_;
#pragma unroll 1
    for (int tt = 0; tt < NT_; ++tt) {
      if (tt < 51) {
        sa += (float)bins[0][tt][tid] * ISCL_;
        sc += (float)bins[1][tt][tid] * ISCL_;
      }
      float mv = (float)tt * DT_ * sa - sc;
      if (cnd == NT_ && mv >= 1.0f) cnd = tt;
    }
    cnd = min(cnd, NT_ - 1);                   // forced spike at last step
    idx1[((size_t)b << 10) + (jg << 6) + tid] = (uint8_t)cnd;
  }
}

// ---------------------------------------------------------------------------
// Layer-2 (r20's no-LDS version): block = (b,j), 4 waves split the i-range;
// lane = t.  W2[j][i] and idx1[b][i] are WAVE-UNIFORM -> uniform float4/u32
// loads, h*DT converted inline.  Zero per-iter DS.
// ---------------------------------------------------------------------------
__global__ __launch_bounds__(256) void k_main2(const uint8_t* __restrict__ idx1,
                                               const float* __restrict__ W2,
                                               float* __restrict__ out) {
  __shared__ float part[4][3][64];
  const int blk = blockIdx.x;          // 640
  const int b   = blk / 10;
  const int j   = blk - b * 10;
  const int tid = threadIdx.x;
  const int lane = tid & 63, wvv = tid >> 6;

  const float4*   __restrict__ w4 = (const float4*)(W2 + (size_t)j * F1_);
  const uint32_t* __restrict__ h4 = (const uint32_t*)(idx1 + ((size_t)b << 10));

  const float tl0 = (float)lane * DT_;
  const float tl1 = (float)(lane + 64) * DT_;
  const float tl2 = (float)(lane + 128) * DT_;
  float m0 = 0.f, m1 = 0.f, m2 = 0.f;
  const int q0 = wvv * 64;
#pragma unroll 4
  for (int q = q0; q < q0 + 64; ++q) {          // 4 i's per iter
    float4   w  = w4[q];                        // uniform
    uint32_t hh = h4[q];                        // uniform
#define E2(we_, sh_) {                                                        \
      float tiv = (float)((hh >> (sh_)) & 255u) * DT_;                        \
      m0 = fmaf((we_), fmaxf(tl0 - tiv, 0.f), m0);                            \
      m1 = fmaf((we_), fmaxf(tl1 - tiv, 0.f), m1);                            \
      m2 = fmaf((we_), fmaxf(tl2 - tiv, 0.f), m2); }
    E2(w.x, 0); E2(w.y, 8); E2(w.z, 16); E2(w.w, 24);
#undef E2
  }
  part[wvv][0][lane] = m0;
  part[wvv][1][lane] = m1;
  part[wvv][2][lane] = m2;
  __syncthreads();

  if (wvv == 0) {
    m0 = part[0][0][lane] + part[1][0][lane] + part[2][0][lane] + part[3][0][lane];
    m1 = part[0][1][lane] + part[1][1][lane] + part[2][1][lane] + part[3][1][lane];
    m2 = part[0][2][lane] + part[1][2][lane] + part[2][2][lane] + part[3][2][lane];
    unsigned long long b0 = __ballot(m0 >= 1.0f);
    unsigned long long b1 = __ballot(m1 >= 1.0f);
    unsigned long long b2 = __ballot(m2 >= 1.0f);
    b2 &= (1ull << 23) - 1;            // t <= 150
    b2 |= (1ull << 22);                // forced spike at t = 150
    int tres;
    if (b0)      tres = __ffsll((long long)b0) - 1;
    else if (b1) tres = 64 + __ffsll((long long)b1) - 1;
    else         tres = 128 + __ffsll((long long)b2) - 1;
    if (lane == 0) out[(size_t)b * F2_ + j] = (float)tres * DT_;
  }
}

}  // namespace

// ---------------------------------------------------------------------------
extern "C" void kernel_launch(void* const* d_in, const int* in_sizes, int n_in,
                              void* d_out, int out_size, void* d_ws, size_t ws_size,
                              hipStream_t stream) {
  const float* ti = (const float*)d_in[0];   // [64][1876]
  const float* W1 = (const float*)d_in[1];   // [1024][1876]
  const float* W2 = (const float*)d_in[2];   // [10][1024]
  float* out = (float*)d_out;                // [64][10]

  char* ws = (char*)d_ws;
  int4*     W1iT4 = (int4*)(ws + OFF_W1I4);
  uint16_t* koff  = (uint16_t*)(ws + OFF_KOFF);
  float*    tvs   = (float*)(ws + OFF_TV);
  uint8_t*  idx1  = (uint8_t*)(ws + OFF_IDX1);

  hipLaunchKernelGGL(k_prep,  dim3(NBLK_T + NBLK_R), dim3(256), 0, stream,
                     W1, ti, W1iT4, koff, tvs);
  hipLaunchKernelGGL(k_main1, dim3(1024), dim3(512), 0, stream,
                     koff, tvs, W1iT4, idx1);
  hipLaunchKernelGGL(k_main2, dim3(640),  dim3(256), 0, stream, idx1, W2, out);
}